// Round 14
// baseline (83.856 us; speedup 1.0000x reference)
//
#include <hip/hip_runtime.h>
#include <math.h>
#include <stdint.h>

// Problem dims
#define NB  8
#define NC  256
#define NHW 4096   // H*W
#define NK  512

// d_out float offsets (outputs concatenated in return order)
#define OFF_SEL 0ULL
#define OFF_CW  8388608ULL              // NB*NC*NHW
#define OFF_KLD 8421376ULL              // + NB*NHW
#define OFF_MAT 8421377ULL              // + 1
#define MAT_COUNT 16777216ULL           // NB*NK*NHW
#define OUT_TOTAL (OFF_MAT + MAT_COUNT) // 25198593

typedef float f4v __attribute__((ext_vector_type(4)));

// ws layout: double sw[512]; double kld_accum; unsigned ticket;  (4112 bytes)

// DPP helpers: xor1=0xB1, xor2=0x4E, xor7(row_half_mirror)=0x141, xor15(row_mirror)=0x140
template <int C>
__device__ __forceinline__ float fdpp(float x) {
    return __int_as_float(__builtin_amdgcn_update_dpp(0, __float_as_int(x), C, 0xF, 0xF, true));
}
template <int C>
__device__ __forceinline__ int idpp(int x) {
    return __builtin_amdgcn_update_dpp(0, x, C, 0xF, 0xF, true);
}
__device__ __forceinline__ float fswz16(float x) {   // lane ^ 16
    return __int_as_float(__builtin_amdgcn_ds_swizzle(__float_as_int(x), 0x401F));
}
__device__ __forceinline__ int iswz16(int x) {
    return __builtin_amdgcn_ds_swizzle(x, 0x401F);
}

// Fused: zero-fill mat region (NT float4 stream) + codebook channel-sum prep
// (blocks 0..127) + ws accumulator/ticket zeroing (block 0).  [r13-proven]
__global__ void zprep(const float* __restrict__ cb, double* __restrict__ ws,
                      float* __restrict__ out) {
    const size_t base4 = 2105345ULL;            // 8421380/4 : first 16B-aligned float4
    const size_t n4    = 4194303ULL;
    size_t i = (size_t)blockIdx.x * blockDim.x + threadIdx.x;
    const size_t stride = (size_t)gridDim.x * blockDim.x;
    f4v* o4 = reinterpret_cast<f4v*>(out) + base4;
    const f4v z = {0.f, 0.f, 0.f, 0.f};
    for (; i < n4; i += stride) __builtin_nontemporal_store(z, o4 + i);
    if (blockIdx.x == 0 && threadIdx.x < 4) {
        out[OFF_MAT + threadIdx.x] = 0.f;       // head floats
        if (threadIdx.x == 0) {
            out[OUT_TOTAL - 1] = 0.f;           // tail float
            ws[NK] = 0.0;                       // kld accumulator
            reinterpret_cast<unsigned*>(ws + NK + 1)[0] = 0u;   // ticket
        }
    }
    if (blockIdx.x < 128) {                     // codebook prep
        const int l = threadIdx.x & 63;
        const int w = threadIdx.x >> 6;
        const int k = blockIdx.x * 4 + w;
        const float4 v = *reinterpret_cast<const float4*>(cb + (size_t)k * NC + l * 4);
        double s = (double)v.x + (double)v.y + (double)v.z + (double)v.w;
        #pragma unroll
        for (int off = 32; off > 0; off >>= 1) s += __shfl_xor(s, off);
        if (l == 0) ws[k] = s;
    }
}

// Wave-per-token, r12 skeleton + PAIRWISE token interleave (2 tokens/iteration,
// independent chains hide each other's DS latency). Loop NOT unrolled (I-cache).
__global__ void __launch_bounds__(512, 4)
gs_main(const float* __restrict__ feats, const float* __restrict__ gumbel,
        const float* __restrict__ cb, double* __restrict__ ws,
        float* __restrict__ out) {
    __shared__ double part[8][64];
    __shared__ float  sw_f[NK];
    __shared__ double sf_d[64];
    __shared__ float  sf_f[64];
    __shared__ int    kcnt[64];
    __shared__ int    klist[64][25];
    __shared__ float  wlist[64][25];
    __shared__ double kldp[8];

    const int tid = threadIdx.x;
    const int l   = tid & 63;
    const int w   = tid >> 6;
    const int b   = blockIdx.x >> 6;
    const int n0  = (blockIdx.x & 63) * 64;

    // ---- Phase A: sf[tok] = channel sum (f64); sw -> LDS f32 ----
    {
        const float* fp = feats + ((size_t)b * NC + w * 32) * NHW + n0 + l;
        double s = 0.0;
        #pragma unroll
        for (int i = 0; i < 32; ++i) s += (double)fp[(size_t)i * NHW];
        part[w][l] = s;
        sw_f[tid] = (float)ws[tid];
        __syncthreads();
        if (tid < 64) {
            double a = 0.0;
            #pragma unroll
            for (int i = 0; i < 8; ++i) a += part[i][tid];
            sf_d[tid] = a; sf_f[tid] = (float)a;
            kcnt[tid] = 0;
        }
        __syncthreads();
    }

    // hoist this lane's 8 sw values (k = l + 64*jj)
    float swreg[8];
    #pragma unroll
    for (int jj = 0; jj < 8; ++jj) swreg[jj] = sw_f[l + 64 * jj];

    double kld_wave = 0.0;
    const float* gbase = gumbel + ((size_t)(b * NHW) + n0 + w * 8) * NK;
    float gcA[8], gcB[8], gnA[8], gnB[8];
    #pragma unroll
    for (int jj = 0; jj < 8; ++jj) {
        gcA[jj] = gbase[l + 64 * jj];
        gcB[jj] = gbase[NK + l + 64 * jj];
    }

    #pragma unroll 1
    for (int i = 0; i < 4; ++i) {              // 4 pairs of tokens
        const int ttA = w * 8 + 2 * i;
        const int ttB = ttA + 1;
        if (i < 3) {                           // prefetch next pair
            const float* gp = gbase + (size_t)(2 * i + 2) * NK;
            #pragma unroll
            for (int jj = 0; jj < 8; ++jj) {
                gnA[jj] = gp[l + 64 * jj];
                gnB[jj] = gp[NK + l + 64 * jj];
            }
        }
        const float sfA = sf_f[ttA], sfB = sf_f[ttB];
        float yA[8], yB[8];
        float MA = -1.0e30f, MB = -1.0e30f, YSA = -1.0e30f, YSB = -1.0e30f;
        int   KA = 0, KBi = 0;
        float EA = 0.f, EB = 0.f, TA = 0.f, TB = 0.f;
        #pragma unroll
        for (int jj = 0; jj < 8; ++jj) {       // two independent chains -> ILP
            const int k = l + 64 * jj;
            const float dA = sfA - swreg[jj];
            const float dB = sfB - swreg[jj];
            const float lgA = __expf(-dA * dA);
            const float lgB = __expf(-dB * dB);
            const float yyA = lgA + gcA[jj];
            const float yyB = lgB + gcB[jj];
            yA[jj] = yyA; yB[jj] = yyB;
            const float hA = fmaf(lgA, fmaf(lgA, fmaf(lgA, fmaf(lgA,
                              1.f/120.f, 1.f/24.f), 1.f/6.f), 0.5f), 1.f);
            const float hB = fmaf(lgB, fmaf(lgB, fmaf(lgB, fmaf(lgB,
                              1.f/120.f, 1.f/24.f), 1.f/6.f), 0.5f), 1.f);
            const float xhA = lgA * hA, xhB = lgB * hB;
            EA += xhA; EB += xhB;
            TA = fmaf(lgA, 1.f + xhA, TA);
            TB = fmaf(lgB, 1.f + xhB, TB);
            if (yyA > MA) { YSA = MA; MA = yyA; KA = k; } else YSA = fmaxf(YSA, yyA);
            if (yyB > MB) { YSB = MB; MB = yyB; KBi = k; } else YSB = fmaxf(YSB, yyB);
        }
        // merged 64-lane reduce, both tokens interleaved: 4 DPP + swizzle + shfl
        #define BSTEP2(GF, GI) { \
            const float oMA = GF(MA); const int oKA = GI(KA); \
            const float oYA = GF(YSA); const float oEA = GF(EA); const float oTA = GF(TA); \
            const float oMB = GF(MB); const int oKB = GI(KBi); \
            const float oYB = GF(YSB); const float oEB = GF(EB); const float oTB = GF(TB); \
            const float nyA = fmaxf(fmaxf(YSA, oYA), fminf(MA, oMA)); \
            const float nyB = fmaxf(fmaxf(YSB, oYB), fminf(MB, oMB)); \
            if (oMA > MA || (oMA == MA && oKA < KA)) { MA = oMA; KA = oKA; } \
            if (oMB > MB || (oMB == MB && oKB < KBi)) { MB = oMB; KBi = oKB; } \
            YSA = nyA; YSB = nyB; EA += oEA; EB += oEB; TA += oTA; TB += oTB; }
        #define SH32(x) __shfl_xor(x, 32)
        BSTEP2(fdpp<0xB1>,  idpp<0xB1>)
        BSTEP2(fdpp<0x4E>,  idpp<0x4E>)
        BSTEP2(fdpp<0x141>, idpp<0x141>)
        BSTEP2(fdpp<0x140>, idpp<0x140>)
        BSTEP2(fswz16,      iswz16)
        BSTEP2(SH32,        SH32)
        #undef SH32
        #undef BSTEP2
        EA += 512.f; EB += 512.f;

        // rare exact f64 argmax (wave-uniform), one copy per pair-slot
        #pragma unroll
        for (int tsel = 0; tsel < 2; ++tsel) {
            const float gapM  = tsel ? MB : MA;
            const float gapYS = tsel ? YSB : YSA;
            if (gapM - gapYS < 5e-3f) {
                const int tt = tsel ? ttB : ttA;
                const double sfd = sf_d[tt];
                double ym64 = -1.0e300; int kb64 = 0;
                #pragma unroll
                for (int jj = 0; jj < 8; ++jj) {
                    const int k = l + 64 * jj;
                    const double dd = sfd - ws[k];
                    const double aff = dd * dd;
                    const double lg = (aff < 45.0) ? exp(-aff) : 0.0;   // <3e-20 invisible
                    const double yy = lg + (double)(tsel ? gcB[jj] : gcA[jj]);
                    if (yy > ym64) { ym64 = yy; kb64 = k; }
                }
                #pragma unroll
                for (int off = 1; off < 64; off <<= 1) {
                    const double oy = __shfl_xor(ym64, off);
                    const int    ok = __shfl_xor(kb64, off);
                    if (oy > ym64 || (oy == ym64 && ok < kb64)) { ym64 = oy; kb64 = ok; }
                }
                if (tsel) KBi = kb64; else KA = kb64;
            }
        }
        if (l == 0) {
            out[OFF_CW + (size_t)b * NHW + n0 + ttA] = (float)KA;
            out[OFF_CW + (size_t)b * NHW + n0 + ttB] = (float)KBi;
            kld_wave += (double)(TA / EA + 6.2383246250395075f - logf(EA));
            kld_wave += (double)(TB / EB + 6.2383246250395075f - logf(EB));
        }
        // candidates: y > M-0.17 (<=> p > 4e-8), ~1.3/token
        const float thrA = MA - 0.17f, thrB = MB - 0.17f;
        #pragma unroll
        for (int jj = 0; jj < 8; ++jj) {
            if (yA[jj] > thrA) {
                const float p = __expf((yA[jj] - MA) * 100.0f);
                const int idx = atomicAdd(&kcnt[ttA], 1);
                if (idx < 24) { klist[ttA][idx] = l + 64 * jj; wlist[ttA][idx] = p; }
            }
            if (yB[jj] > thrB) {
                const float p = __expf((yB[jj] - MB) * 100.0f);
                const int idx = atomicAdd(&kcnt[ttB], 1);
                if (idx < 24) { klist[ttB][idx] = l + 64 * jj; wlist[ttB][idx] = p; }
            }
        }
        #pragma unroll
        for (int jj = 0; jj < 8; ++jj) { gcA[jj] = gnA[jj]; gcB[jj] = gnB[jj]; }
    }
    if (l == 0) kldp[w] = kld_wave;
    __syncthreads();
    if (tid == 0) {
        double acc = 0.0;
        #pragma unroll
        for (int i = 0; i < 8; ++i) acc += kldp[i];
        atomicAdd(&ws[NK], acc);
        __threadfence();
        unsigned* ctr = reinterpret_cast<unsigned*>(ws + NK + 1);
        const unsigned t = atomicAdd(ctr, 1u);
        if (t == 511u) {                        // last block finalizes kld
            __threadfence();
            const double tot = atomicAdd(&ws[NK], 0.0);   // atomic read
            out[OFF_KLD] = (float)(tot * (1.0 / 32768.0));
        }
    }

    // ---- Finalize: per-token S from list, normalize, sparse mat scatter ----
    if (tid < 64) {
        const int cnt = min(kcnt[tid], 24);
        float S = 0.f;
        for (int e = 0; e < cnt; ++e) S += wlist[tid][e];
        const float inv = 1.f / S;              // excluded mass < 2e-5 rel
        float* orow = out + OFF_MAT + ((size_t)b * NK) * NHW + n0 + tid;
        for (int e = 0; e < cnt; ++e) {
            const float wgt = wlist[tid][e] * inv;
            wlist[tid][e] = wgt;
            orow[(size_t)klist[tid][e] * NHW] = wgt;      // scatter on zeroed bg
        }
        kcnt[tid] = cnt;
    }
    __syncthreads();

    // ---- Phase D: sel_codewords from sparse list (NT stores, 256B runs) ----
    {
        const int cnt = kcnt[l];
        #pragma unroll
        for (int half = 0; half < 2; ++half) {
            float acc[16];
            #pragma unroll
            for (int i2 = 0; i2 < 16; ++i2) acc[i2] = 0.f;
            for (int e = 0; e < cnt; ++e) {
                const int k = klist[l][e];
                const float wgt = wlist[l][e];
                const float4* cr = reinterpret_cast<const float4*>(
                    cb + (size_t)k * NC + w * 32 + half * 16);
                #pragma unroll
                for (int q = 0; q < 4; ++q) {
                    const float4 v = cr[q];
                    acc[q * 4 + 0] += wgt * v.x; acc[q * 4 + 1] += wgt * v.y;
                    acc[q * 4 + 2] += wgt * v.z; acc[q * 4 + 3] += wgt * v.w;
                }
            }
            float* basep = out + OFF_SEL + ((size_t)b * NC + w * 32 + half * 16) * NHW + n0 + l;
            #pragma unroll
            for (int i2 = 0; i2 < 16; ++i2)
                __builtin_nontemporal_store(acc[i2], basep + (size_t)i2 * NHW);
        }
    }
}

extern "C" void kernel_launch(void* const* d_in, const int* in_sizes, int n_in,
                              void* d_out, int out_size, void* d_ws, size_t ws_size,
                              hipStream_t stream) {
    const float* feats = (const float*)d_in[0];
    const float* cb    = (const float*)d_in[1];
    const float* gum   = (const float*)d_in[2];
    double* ws = (double*)d_ws;
    float* out = (float*)d_out;
    zprep<<<2048, 256, 0, stream>>>(cb, ws, out);
    gs_main<<<512, 512, 0, stream>>>(feats, gum, cb, ws, out);
}

// Round 15
// 72.869 us; speedup vs baseline: 1.1508x; 1.1508x over previous
//
#include <hip/hip_runtime.h>
#include <math.h>
#include <stdint.h>

// Problem dims
#define NB  8
#define NC  256
#define NHW 4096   // H*W
#define NK  512

// d_out float offsets (outputs concatenated in return order)
#define OFF_SEL 0ULL
#define OFF_CW  8388608ULL              // NB*NC*NHW
#define OFF_KLD 8421376ULL              // + NB*NHW
#define OFF_MAT 8421377ULL              // + 1
#define MAT_COUNT 16777216ULL           // NB*NK*NHW
#define OUT_TOTAL (OFF_MAT + MAT_COUNT) // 25198593

typedef float f4v __attribute__((ext_vector_type(4)));

// ws layout: double sw[512]; double kld_accum; unsigned ticket;  (4112 bytes)

// DPP helpers: xor1=0xB1, xor2=0x4E, xor7(row_half_mirror)=0x141, xor15(row_mirror)=0x140
template <int C>
__device__ __forceinline__ float fdpp(float x) {
    return __int_as_float(__builtin_amdgcn_update_dpp(0, __float_as_int(x), C, 0xF, 0xF, true));
}
template <int C>
__device__ __forceinline__ int idpp(int x) {
    return __builtin_amdgcn_update_dpp(0, x, C, 0xF, 0xF, true);
}
__device__ __forceinline__ float fswz16(float x) {   // lane ^ 16
    return __int_as_float(__builtin_amdgcn_ds_swizzle(__float_as_int(x), 0x401F));
}
__device__ __forceinline__ int iswz16(int x) {
    return __builtin_amdgcn_ds_swizzle(x, 0x401F);
}

// Fused: zero-fill mat region (NT float4 stream) + codebook channel-sum prep
// (blocks 0..127) + ws accumulator/ticket zeroing (block 0).  [proven r13/r14]
__global__ void zprep(const float* __restrict__ cb, double* __restrict__ ws,
                      float* __restrict__ out) {
    const size_t base4 = 2105345ULL;            // 8421380/4 : first 16B-aligned float4
    const size_t n4    = 4194303ULL;
    size_t i = (size_t)blockIdx.x * blockDim.x + threadIdx.x;
    const size_t stride = (size_t)gridDim.x * blockDim.x;
    f4v* o4 = reinterpret_cast<f4v*>(out) + base4;
    const f4v z = {0.f, 0.f, 0.f, 0.f};
    for (; i < n4; i += stride) __builtin_nontemporal_store(z, o4 + i);
    if (blockIdx.x == 0 && threadIdx.x < 4) {
        out[OFF_MAT + threadIdx.x] = 0.f;       // head floats
        if (threadIdx.x == 0) {
            out[OUT_TOTAL - 1] = 0.f;           // tail float
            ws[NK] = 0.0;                       // kld accumulator
            reinterpret_cast<unsigned*>(ws + NK + 1)[0] = 0u;   // ticket
        }
    }
    if (blockIdx.x < 128) {                     // codebook prep
        const int l = threadIdx.x & 63;
        const int w = threadIdx.x >> 6;
        const int k = blockIdx.x * 4 + w;
        const float4 v = *reinterpret_cast<const float4*>(cb + (size_t)k * NC + l * 4);
        double s = (double)v.x + (double)v.y + (double)v.z + (double)v.w;
        #pragma unroll
        for (int off = 32; off > 0; off >>= 1) s += __shfl_xor(s, off);
        if (l == 0) ws[k] = s;
    }
}

// gs_main: EXACT r12 structure (best measured: 48 VGPR, no spills, 34 MB write),
// with the r13/r14-proven last-block kld finalize replacing the fin kernel.
__global__ void __launch_bounds__(512, 4)
gs_main(const float* __restrict__ feats, const float* __restrict__ gumbel,
        const float* __restrict__ cb, double* __restrict__ ws,
        float* __restrict__ out) {
    __shared__ double part[8][64];
    __shared__ float  sw_f[NK];
    __shared__ double sf_d[64];
    __shared__ float  sf_f[64];
    __shared__ int    kcnt[64];
    __shared__ int    klist[64][25];
    __shared__ float  wlist[64][25];
    __shared__ double kldp[8];

    const int tid = threadIdx.x;
    const int l   = tid & 63;          // lane
    const int w   = tid >> 6;          // wave 0..7
    const int b   = blockIdx.x >> 6;   // 64 blocks per batch
    const int n0  = (blockIdx.x & 63) * 64;

    // ---- Phase A: sf[tok] = sum_c feats[b,c,n0+tok] (f64); sw -> LDS f32 ----
    {
        const float* fp = feats + ((size_t)b * NC + w * 32) * NHW + n0 + l;
        double s = 0.0;
        #pragma unroll
        for (int i = 0; i < 32; ++i) s += (double)fp[(size_t)i * NHW];
        part[w][l] = s;
        sw_f[tid] = (float)ws[tid];
        __syncthreads();
        if (tid < 64) {
            double a = 0.0;
            #pragma unroll
            for (int i = 0; i < 8; ++i) a += part[i][tid];
            sf_d[tid] = a; sf_f[tid] = (float)a;
            kcnt[tid] = 0;
        }
        __syncthreads();
    }

    // hoist this lane's 8 sw values (same for all its tokens)
    float swreg[8];
    #pragma unroll
    for (int jj = 0; jj < 8; ++jj) swreg[jj] = sw_f[l + 64 * jj];

    // ---- Phase B: 8 tokens per wave; k = l + 64*jj (256B coalesced g loads) ----
    double kld_wave = 0.0;
    float gc[8], gn[8];
    {
        const float* gp = gumbel + ((size_t)(b * NHW) + n0 + w * 8) * NK;
        #pragma unroll
        for (int jj = 0; jj < 8; ++jj) gc[jj] = gp[l + 64 * jj];
    }
    #pragma unroll
    for (int i = 0; i < 8; ++i) {
        const int tt = w * 8 + i;
        const int n  = n0 + tt;
        if (i < 7) {                        // prefetch next token's row
            const float* gpn = gumbel + ((size_t)(b * NHW) + n + 1) * NK;
            #pragma unroll
            for (int jj = 0; jj < 8; ++jj) gn[jj] = gpn[l + 64 * jj];
        }
        const float sft = sf_f[tt];
        float y[8];
        float M = -1.0e30f, YS = -1.0e30f; int KB = 0;
        float E = 0.f, T = 0.f;
        #pragma unroll
        for (int jj = 0; jj < 8; ++jj) {    // hot loop: pure VALU, k ascending
            const int k = l + 64 * jj;
            const float d = sft - swreg[jj];
            const float logit = __expf(-d * d);
            const float yy = logit + gc[jj];
            y[jj] = yy;
            // e^logit - 1 = logit*h (5th order): E rel err ~4e-6
            const float h = fmaf(logit, fmaf(logit, fmaf(logit, fmaf(logit,
                              1.f/120.f, 1.f/24.f), 1.f/6.f), 0.5f), 1.f);
            const float xh = logit * h;
            E += xh;
            T = fmaf(logit, 1.f + xh, T);
            if (yy > M) { YS = M; M = yy; KB = k; }      // strict >: lowest k on ties
            else YS = fmaxf(YS, yy);
        }
        // merged 64-lane reduce: 4 DPP + 1 swizzle + 1 shfl (argmax/2nd/E/T)
        #define BSTEP(GF, GI) { \
            const float oM = GF(M); const int oK = GI(KB); \
            const float oY = GF(YS); const float oE = GF(E); const float oT = GF(T); \
            const float nys = fmaxf(fmaxf(YS, oY), fminf(M, oM)); \
            if (oM > M || (oM == M && oK < KB)) { M = oM; KB = oK; } \
            YS = nys; E += oE; T += oT; }
        BSTEP(fdpp<0xB1>,  idpp<0xB1>)     // xor 1
        BSTEP(fdpp<0x4E>,  idpp<0x4E>)     // xor 2
        BSTEP(fdpp<0x141>, idpp<0x141>)    // xor 7 (row half mirror)
        BSTEP(fdpp<0x140>, idpp<0x140>)    // xor 15 (row mirror)
        BSTEP(fswz16,      iswz16)         // xor 16 (DS)
        #define SH32F(x) __shfl_xor(x, 32)
        #define SH32I(x) __shfl_xor(x, 32)
        BSTEP(SH32F, SH32I)                // xor 32 (DS, cross-half)
        #undef SH32F
        #undef SH32I
        #undef BSTEP
        E += 512.f;

        // rare exact f64 argmax (wave-uniform); f32 y err ~1e-5 << 5e-3 gap
        if (M - YS < 5e-3f) {
            const double sfd = sf_d[tt];
            double ym64 = -1.0e300; int kb64 = 0;
            #pragma unroll
            for (int jj = 0; jj < 8; ++jj) {
                const int k = l + 64 * jj;
                const double dd = sfd - ws[k];
                const double aff = dd * dd;
                const double lg = (aff < 45.0) ? exp(-aff) : 0.0;   // <3e-20 invisible
                const double yy = lg + (double)gc[jj];
                if (yy > ym64) { ym64 = yy; kb64 = k; }
            }
            #pragma unroll
            for (int off = 1; off < 64; off <<= 1) {
                const double oy = __shfl_xor(ym64, off);
                const int    ok = __shfl_xor(kb64, off);
                if (oy > ym64 || (oy == ym64 && ok < kb64)) { ym64 = oy; kb64 = ok; }
            }
            KB = kb64;
        }
        if (l == 0) {
            out[OFF_CW + (size_t)b * NHW + n] = (float)KB;
            // kld_tok = T/E + ln512 - lnE (eps=1e-10 negligible)
            kld_wave += (double)(T / E + 6.2383246250395075f - logf(E));
        }

        // candidates: y > M-0.17 (<=> p > 4e-8, ~1.3/token): exp only when needed
        const float thrM = M - 0.17f;
        #pragma unroll
        for (int jj = 0; jj < 8; ++jj) {
            if (y[jj] > thrM) {
                const float p = __expf((y[jj] - M) * 100.0f);
                const int idx = atomicAdd(&kcnt[tt], 1);
                if (idx < 24) { klist[tt][idx] = l + 64 * jj; wlist[tt][idx] = p; }
            }
        }
        #pragma unroll
        for (int jj = 0; jj < 8; ++jj) gc[jj] = gn[jj];
    }
    if (l == 0) kldp[w] = kld_wave;
    __syncthreads();
    if (tid == 0) {
        double acc = 0.0;
        #pragma unroll
        for (int i = 0; i < 8; ++i) acc += kldp[i];
        atomicAdd(&ws[NK], acc);
        __threadfence();
        unsigned* ctr = reinterpret_cast<unsigned*>(ws + NK + 1);
        const unsigned t = atomicAdd(ctr, 1u);
        if (t == 511u) {                        // last block finalizes kld
            __threadfence();
            const double tot = atomicAdd(&ws[NK], 0.0);   // atomic read
            out[OFF_KLD] = (float)(tot * (1.0 / 32768.0));
        }
    }

    // ---- Finalize: per-token S from list, normalize in LDS, sparse mat scatter ----
    if (tid < 64) {
        const int cnt = min(kcnt[tid], 24);
        float S = 0.f;
        for (int e = 0; e < cnt; ++e) S += wlist[tid][e];
        const float inv = 1.f / S;          // excluded mass < 512*4e-8 = 2e-5 rel
        float* orow = out + OFF_MAT + ((size_t)b * NK) * NHW + n0 + tid;
        for (int e = 0; e < cnt; ++e) {
            const float wgt = wlist[tid][e] * inv;
            wlist[tid][e] = wgt;
            orow[(size_t)klist[tid][e] * NHW] = wgt;   // sparse scatter on zmat bg
        }
        kcnt[tid] = cnt;
    }
    __syncthreads();

    // ---- Phase D: sel_codewords (B,C,N) from sparse list (NT stores, 256B runs) ----
    {
        const int cnt = kcnt[l];            // lane l = token l
        #pragma unroll
        for (int half = 0; half < 2; ++half) {
            float acc[16];
            #pragma unroll
            for (int i2 = 0; i2 < 16; ++i2) acc[i2] = 0.f;
            for (int e = 0; e < cnt; ++e) {
                const int k = klist[l][e];
                const float wgt = wlist[l][e];
                const float4* cr = reinterpret_cast<const float4*>(
                    cb + (size_t)k * NC + w * 32 + half * 16);
                #pragma unroll
                for (int q = 0; q < 4; ++q) {
                    const float4 v = cr[q];
                    acc[q * 4 + 0] += wgt * v.x; acc[q * 4 + 1] += wgt * v.y;
                    acc[q * 4 + 2] += wgt * v.z; acc[q * 4 + 3] += wgt * v.w;
                }
            }
            float* basep = out + OFF_SEL + ((size_t)b * NC + w * 32 + half * 16) * NHW + n0 + l;
            #pragma unroll
            for (int i2 = 0; i2 < 16; ++i2)
                __builtin_nontemporal_store(acc[i2], basep + (size_t)i2 * NHW);
        }
    }
}

extern "C" void kernel_launch(void* const* d_in, const int* in_sizes, int n_in,
                              void* d_out, int out_size, void* d_ws, size_t ws_size,
                              hipStream_t stream) {
    const float* feats = (const float*)d_in[0];
    const float* cb    = (const float*)d_in[1];
    const float* gum   = (const float*)d_in[2];
    double* ws = (double*)d_ws;
    float* out = (float*)d_out;
    zprep<<<2048, 256, 0, stream>>>(cb, ws, out);
    gs_main<<<512, 512, 0, stream>>>(feats, gum, cb, ws, out);
}

// Round 16
// 57.692 us; speedup vs baseline: 1.4535x; 1.2631x over previous
//
#include <hip/hip_runtime.h>
#include <math.h>
#include <stdint.h>

// Problem dims
#define NB  8
#define NC  256
#define NHW 4096   // H*W
#define NK  512

// d_out float offsets (outputs concatenated in return order)
#define OFF_SEL 0ULL
#define OFF_CW  8388608ULL              // NB*NC*NHW
#define OFF_KLD 8421376ULL              // + NB*NHW
#define OFF_MAT 8421377ULL              // + 1
#define MAT_COUNT 16777216ULL           // NB*NK*NHW
#define OUT_TOTAL (OFF_MAT + MAT_COUNT) // 25198593

typedef float f4v __attribute__((ext_vector_type(4)));

// ws layout: double sw[512]; double kld_accum;  (4104 bytes)

// DPP helpers: xor1=0xB1, xor2=0x4E, xor7(row_half_mirror)=0x141, xor15(row_mirror)=0x140
template <int C>
__device__ __forceinline__ float fdpp(float x) {
    return __int_as_float(__builtin_amdgcn_update_dpp(0, __float_as_int(x), C, 0xF, 0xF, true));
}
template <int C>
__device__ __forceinline__ int idpp(int x) {
    return __builtin_amdgcn_update_dpp(0, x, C, 0xF, 0xF, true);
}
__device__ __forceinline__ float fswz16(float x) {   // lane ^ 16
    return __int_as_float(__builtin_amdgcn_ds_swizzle(__float_as_int(x), 0x401F));
}
__device__ __forceinline__ int iswz16(int x) {
    return __builtin_amdgcn_ds_swizzle(x, 0x401F);
}

// Fused: zero-fill mat region (NT float4 stream) + codebook channel-sum prep
// (blocks 0..127) + ws kld zeroing (block 0).  [streaming part proven r13-r15]
__global__ void zprep(const float* __restrict__ cb, double* __restrict__ ws,
                      float* __restrict__ out) {
    const size_t base4 = 2105345ULL;            // 8421380/4 : first 16B-aligned float4
    const size_t n4    = 4194303ULL;
    size_t i = (size_t)blockIdx.x * blockDim.x + threadIdx.x;
    const size_t stride = (size_t)gridDim.x * blockDim.x;
    f4v* o4 = reinterpret_cast<f4v*>(out) + base4;
    const f4v z = {0.f, 0.f, 0.f, 0.f};
    for (; i < n4; i += stride) __builtin_nontemporal_store(z, o4 + i);
    if (blockIdx.x == 0 && threadIdx.x < 4) {
        out[OFF_MAT + threadIdx.x] = 0.f;       // head floats
        if (threadIdx.x == 0) {
            out[OUT_TOTAL - 1] = 0.f;           // tail float
            ws[NK] = 0.0;                       // kld accumulator
        }
    }
    if (blockIdx.x < 128) {                     // codebook prep
        const int l = threadIdx.x & 63;
        const int w = threadIdx.x >> 6;
        const int k = blockIdx.x * 4 + w;
        const float4 v = *reinterpret_cast<const float4*>(cb + (size_t)k * NC + l * 4);
        double s = (double)v.x + (double)v.y + (double)v.z + (double)v.w;
        #pragma unroll
        for (int off = 32; off > 0; off >>= 1) s += __shfl_xor(s, off);
        if (l == 0) ws[k] = s;
    }
}

// gs_main: EXACT r12 structure (measured best: 48 VGPR, no spills, 34 MB write,
// profiled ~59.5 us). No device fences; kld via one atomicAdd per block.
__global__ void __launch_bounds__(512, 4)
gs_main(const float* __restrict__ feats, const float* __restrict__ gumbel,
        const float* __restrict__ cb, double* __restrict__ ws,
        float* __restrict__ out) {
    __shared__ double part[8][64];
    __shared__ float  sw_f[NK];
    __shared__ double sf_d[64];
    __shared__ float  sf_f[64];
    __shared__ int    kcnt[64];
    __shared__ int    klist[64][25];
    __shared__ float  wlist[64][25];
    __shared__ double kldp[8];

    const int tid = threadIdx.x;
    const int l   = tid & 63;          // lane
    const int w   = tid >> 6;          // wave 0..7
    const int b   = blockIdx.x >> 6;   // 64 blocks per batch
    const int n0  = (blockIdx.x & 63) * 64;

    // ---- Phase A: sf[tok] = sum_c feats[b,c,n0+tok] (f64); sw -> LDS f32 ----
    {
        const float* fp = feats + ((size_t)b * NC + w * 32) * NHW + n0 + l;
        double s = 0.0;
        #pragma unroll
        for (int i = 0; i < 32; ++i) s += (double)fp[(size_t)i * NHW];
        part[w][l] = s;
        sw_f[tid] = (float)ws[tid];
        __syncthreads();
        if (tid < 64) {
            double a = 0.0;
            #pragma unroll
            for (int i = 0; i < 8; ++i) a += part[i][tid];
            sf_d[tid] = a; sf_f[tid] = (float)a;
            kcnt[tid] = 0;
        }
        __syncthreads();
    }

    // hoist this lane's 8 sw values (same for all its tokens)
    float swreg[8];
    #pragma unroll
    for (int jj = 0; jj < 8; ++jj) swreg[jj] = sw_f[l + 64 * jj];

    // ---- Phase B: 8 tokens per wave; k = l + 64*jj (256B coalesced g loads) ----
    double kld_wave = 0.0;
    float gc[8], gn[8];
    {
        const float* gp = gumbel + ((size_t)(b * NHW) + n0 + w * 8) * NK;
        #pragma unroll
        for (int jj = 0; jj < 8; ++jj) gc[jj] = gp[l + 64 * jj];
    }
    #pragma unroll
    for (int i = 0; i < 8; ++i) {
        const int tt = w * 8 + i;
        const int n  = n0 + tt;
        if (i < 7) {                        // prefetch next token's row
            const float* gpn = gumbel + ((size_t)(b * NHW) + n + 1) * NK;
            #pragma unroll
            for (int jj = 0; jj < 8; ++jj) gn[jj] = gpn[l + 64 * jj];
        }
        const float sft = sf_f[tt];
        float y[8];
        float M = -1.0e30f, YS = -1.0e30f; int KB = 0;
        float E = 0.f, T = 0.f;
        #pragma unroll
        for (int jj = 0; jj < 8; ++jj) {    // hot loop: pure VALU, k ascending
            const int k = l + 64 * jj;
            const float d = sft - swreg[jj];
            const float logit = __expf(-d * d);
            const float yy = logit + gc[jj];
            y[jj] = yy;
            // e^logit - 1 = logit*h (5th order): E rel err ~4e-6
            const float h = fmaf(logit, fmaf(logit, fmaf(logit, fmaf(logit,
                              1.f/120.f, 1.f/24.f), 1.f/6.f), 0.5f), 1.f);
            const float xh = logit * h;
            E += xh;
            T = fmaf(logit, 1.f + xh, T);
            if (yy > M) { YS = M; M = yy; KB = k; }      // strict >: lowest k on ties
            else YS = fmaxf(YS, yy);
        }
        // merged 64-lane reduce: 4 DPP + 1 swizzle + 1 shfl (argmax/2nd/E/T)
        #define BSTEP(GF, GI) { \
            const float oM = GF(M); const int oK = GI(KB); \
            const float oY = GF(YS); const float oE = GF(E); const float oT = GF(T); \
            const float nys = fmaxf(fmaxf(YS, oY), fminf(M, oM)); \
            if (oM > M || (oM == M && oK < KB)) { M = oM; KB = oK; } \
            YS = nys; E += oE; T += oT; }
        BSTEP(fdpp<0xB1>,  idpp<0xB1>)     // xor 1
        BSTEP(fdpp<0x4E>,  idpp<0x4E>)     // xor 2
        BSTEP(fdpp<0x141>, idpp<0x141>)    // xor 7 (row half mirror)
        BSTEP(fdpp<0x140>, idpp<0x140>)    // xor 15 (row mirror)
        BSTEP(fswz16,      iswz16)         // xor 16 (DS)
        #define SH32F(x) __shfl_xor(x, 32)
        #define SH32I(x) __shfl_xor(x, 32)
        BSTEP(SH32F, SH32I)                // xor 32 (DS, cross-half)
        #undef SH32F
        #undef SH32I
        #undef BSTEP
        E += 512.f;

        // rare exact f64 argmax (wave-uniform); f32 y err ~1e-5 << 5e-3 gap
        if (M - YS < 5e-3f) {
            const double sfd = sf_d[tt];
            double ym64 = -1.0e300; int kb64 = 0;
            #pragma unroll
            for (int jj = 0; jj < 8; ++jj) {
                const int k = l + 64 * jj;
                const double dd = sfd - ws[k];
                const double aff = dd * dd;
                const double lg = (aff < 45.0) ? exp(-aff) : 0.0;   // <3e-20 invisible
                const double yy = lg + (double)gc[jj];
                if (yy > ym64) { ym64 = yy; kb64 = k; }
            }
            #pragma unroll
            for (int off = 1; off < 64; off <<= 1) {
                const double oy = __shfl_xor(ym64, off);
                const int    ok = __shfl_xor(kb64, off);
                if (oy > ym64 || (oy == ym64 && ok < kb64)) { ym64 = oy; kb64 = ok; }
            }
            KB = kb64;
        }
        if (l == 0) {
            out[OFF_CW + (size_t)b * NHW + n] = (float)KB;
            // kld_tok = T/E + ln512 - lnE (eps=1e-10 negligible)
            kld_wave += (double)(T / E + 6.2383246250395075f - logf(E));
        }

        // candidates: y > M-0.17 (<=> p > 4e-8, ~1.3/token): exp only when needed
        const float thrM = M - 0.17f;
        #pragma unroll
        for (int jj = 0; jj < 8; ++jj) {
            if (y[jj] > thrM) {
                const float p = __expf((y[jj] - M) * 100.0f);
                const int idx = atomicAdd(&kcnt[tt], 1);
                if (idx < 24) { klist[tt][idx] = l + 64 * jj; wlist[tt][idx] = p; }
            }
        }
        #pragma unroll
        for (int jj = 0; jj < 8; ++jj) gc[jj] = gn[jj];
    }
    if (l == 0) kldp[w] = kld_wave;
    __syncthreads();
    if (tid == 0) {
        double acc = 0.0;
        #pragma unroll
        for (int i = 0; i < 8; ++i) acc += kldp[i];
        atomicAdd(&ws[NK], acc);            // one global atomic per block (no fence)
    }

    // ---- Finalize: per-token S from list, normalize in LDS, sparse mat scatter ----
    if (tid < 64) {
        const int cnt = min(kcnt[tid], 24);
        float S = 0.f;
        for (int e = 0; e < cnt; ++e) S += wlist[tid][e];
        const float inv = 1.f / S;          // excluded mass < 512*4e-8 = 2e-5 rel
        float* orow = out + OFF_MAT + ((size_t)b * NK) * NHW + n0 + tid;
        for (int e = 0; e < cnt; ++e) {
            const float wgt = wlist[tid][e] * inv;
            wlist[tid][e] = wgt;
            orow[(size_t)klist[tid][e] * NHW] = wgt;   // sparse scatter on zprep bg
        }
        kcnt[tid] = cnt;
    }
    __syncthreads();

    // ---- Phase D: sel_codewords (B,C,N) from sparse list (NT stores, 256B runs) ----
    {
        const int cnt = kcnt[l];            // lane l = token l
        #pragma unroll
        for (int half = 0; half < 2; ++half) {
            float acc[16];
            #pragma unroll
            for (int i2 = 0; i2 < 16; ++i2) acc[i2] = 0.f;
            for (int e = 0; e < cnt; ++e) {
                const int k = klist[l][e];
                const float wgt = wlist[l][e];
                const float4* cr = reinterpret_cast<const float4*>(
                    cb + (size_t)k * NC + w * 32 + half * 16);
                #pragma unroll
                for (int q = 0; q < 4; ++q) {
                    const float4 v = cr[q];
                    acc[q * 4 + 0] += wgt * v.x; acc[q * 4 + 1] += wgt * v.y;
                    acc[q * 4 + 2] += wgt * v.z; acc[q * 4 + 3] += wgt * v.w;
                }
            }
            float* basep = out + OFF_SEL + ((size_t)b * NC + w * 32 + half * 16) * NHW + n0 + l;
            #pragma unroll
            for (int i2 = 0; i2 < 16; ++i2)
                __builtin_nontemporal_store(acc[i2], basep + (size_t)i2 * NHW);
        }
    }
}

__global__ void gumbel_fin(const double* __restrict__ ws, float* __restrict__ out) {
    out[OFF_KLD] = (float)(ws[NK] * (1.0 / 32768.0));
}

extern "C" void kernel_launch(void* const* d_in, const int* in_sizes, int n_in,
                              void* d_out, int out_size, void* d_ws, size_t ws_size,
                              hipStream_t stream) {
    const float* feats = (const float*)d_in[0];
    const float* cb    = (const float*)d_in[1];
    const float* gum   = (const float*)d_in[2];
    double* ws = (double*)d_ws;
    float* out = (float*)d_out;
    zprep<<<2048, 256, 0, stream>>>(cb, ws, out);
    gs_main<<<512, 512, 0, stream>>>(feats, gum, cb, ws, out);
    gumbel_fin<<<1, 1, 0, stream>>>(ws, out);
}